// Round 12
// baseline (1275.506 us; speedup 1.0000x reference)
//
#include <hip/hip_runtime.h>
#include <hip/hip_bf16.h>

// RelationalTransformer forward on MI355X (gfx950). Round 11.
// Revert to R8 structure (measured best: 1134us). Sparse-sort path removed
// (sort_ids was 84us/call; sparse machinery net-negative). Additions:
// nontemporal load/store in cvt_all (streaming weights), s_setprio(1) around
// attention MFMA clusters (T5, +4-7% measured on attn-like kernels).

typedef __attribute__((ext_vector_type(4))) float f32x4;
typedef __attribute__((ext_vector_type(8))) short s16x8;
typedef __attribute__((ext_vector_type(4))) short s16x4;
typedef __attribute__((ext_vector_type(16))) short s16x16;

#define SEQ 1024
#define DM 512
#define MTOT 4096
#define EPSV 1.1920929e-07f
#define LOG2E 1.44269504088896f

static __device__ __forceinline__ float b2f(short s) {
  unsigned u = ((unsigned)(unsigned short)s) << 16;
  return __builtin_bit_cast(float, u);
}
static __device__ __forceinline__ short f2b(float f) {
  unsigned u = __builtin_bit_cast(unsigned, f);
  u = (u + 0x7fffu + ((u >> 16) & 1u)) >> 16;  // RNE; inputs never NaN
  return (short)(unsigned short)u;
}

#define MFMA_BF16(a, b, c) __builtin_amdgcn_mfma_f32_16x16x32_bf16((a), (b), (c), 0, 0, 0)
#define GLLDS(gp, lp)                                                                        \
  __builtin_amdgcn_global_load_lds((const __attribute__((address_space(1))) unsigned*)(gp),  \
                                   (__attribute__((address_space(3))) unsigned*)(lp), 16, 0, 0)
#define GLLDS4(gp, lp)                                                                       \
  __builtin_amdgcn_global_load_lds((const __attribute__((address_space(1))) unsigned*)(gp),  \
                                   (__attribute__((address_space(3))) unsigned*)(lp), 4, 0, 0)

// ---------------- merged weight conversion, 64B/thread, gamma folded, nontemporal ----------------
__global__ void cvt_all(const f32x4* __restrict__ wq, const f32x4* __restrict__ wk,
                        const f32x4* __restrict__ wv, const f32x4* __restrict__ wo,
                        const f32x4* __restrict__ w1, const f32x4* __restrict__ w3,
                        const f32x4* __restrict__ w2, const float* __restrict__ g_attn,
                        const float* __restrict__ g_ffn, short* __restrict__ wqkv,
                        short* __restrict__ wob, short* __restrict__ w13,
                        short* __restrict__ w2b) {
  int i0 = (blockIdx.x * 256 + threadIdx.x) * 4;
  int which = blockIdx.y;
  s16x16 o;
  if (which < 3) {
    const f32x4* src = which == 0 ? wq : (which == 1 ? wk : wv);
    f32x4 v[4];
#pragma unroll
    for (int c = 0; c < 4; c++) v[c] = __builtin_nontemporal_load(&src[i0 + c]);
    int lr = i0 >> 16, k4 = i0 & 127, n = (i0 >> 7) & 511;
    const float* gp = g_attn + lr * 512 + k4 * 4;
    float sc = (which == 0) ? 0.125f * LOG2E : 1.0f;
#pragma unroll
    for (int c = 0; c < 4; c++)
#pragma unroll
      for (int j = 0; j < 4; j++) o[c * 4 + j] = f2b(v[c][j] * gp[c * 4 + j] * sc);
    __builtin_nontemporal_store(o, (s16x16*)(wqkv + ((size_t)lr * 196608 + (which * 512 + n) * 128 + k4) * 4));
  } else if (which == 3 || which == 6) {
    const f32x4* src = which == 3 ? wo : w2;
    short* dst = which == 3 ? wob : w2b;
    f32x4 v[4];
#pragma unroll
    for (int c = 0; c < 4; c++) v[c] = __builtin_nontemporal_load(&src[i0 + c]);
#pragma unroll
    for (int c = 0; c < 4; c++)
#pragma unroll
      for (int j = 0; j < 4; j++) o[c * 4 + j] = f2b(v[c][j]);
    __builtin_nontemporal_store(o, (s16x16*)(dst + (size_t)i0 * 4));
  } else {
    const f32x4* src = which == 4 ? w1 : w3;
    int off = which - 4;
    f32x4 v[4];
#pragma unroll
    for (int c = 0; c < 4; c++) v[c] = __builtin_nontemporal_load(&src[i0 + c]);
    int l = i0 >> 18, n = (i0 >> 7) & 2047, k4 = i0 & 127;
    const float* gp = g_ffn + l * 512 + k4 * 4;
#pragma unroll
    for (int c = 0; c < 4; c++)
#pragma unroll
      for (int j = 0; j < 4; j++) o[c * 4 + j] = f2b(v[c][j] * gp[c * 4 + j]);
    __builtin_nontemporal_store(o, (s16x16*)(w13 + ((size_t)l * 524288 + (n * 2 + off) * 128 + k4) * 4));
  }
}

// ---------------- init: x copy + bf16 h + sumsq slot0 + zero slots 1..20 ----------------
__global__ void init_kernel(const float* __restrict__ xin, float* __restrict__ x,
                            short* __restrict__ h, float* __restrict__ sbuf) {
  int gid = blockIdx.x * 256 + threadIdx.x;
  if (gid < 20 * 4096) sbuf[4096 + gid] = 0.f;
  int row = blockIdx.x * 4 + (threadIdx.x >> 6);
  int lane = threadIdx.x & 63;
  const float* xr = xin + (size_t)row * DM + lane * 8;
  f32x4 a = *(const f32x4*)xr;
  f32x4 b = *(const f32x4*)(xr + 4);
  float* xo = x + (size_t)row * DM + lane * 8;
  *(f32x4*)xo = a;
  *(f32x4*)(xo + 4) = b;
  s16x8 ho;
#pragma unroll
  for (int j = 0; j < 4; j++) { ho[j] = f2b(a[j]); ho[4 + j] = f2b(b[j]); }
  *(s16x8*)(h + (size_t)row * DM + lane * 8) = ho;
  float ss = a[0]*a[0]+a[1]*a[1]+a[2]*a[2]+a[3]*a[3]+b[0]*b[0]+b[1]*b[1]+b[2]*b[2]+b[3]*b[3];
#pragma unroll
  for (int m = 1; m < 64; m <<= 1) ss += __shfl_xor(ss, m, 64);
  if (lane == 0) sbuf[row] = ss;
}

// ---------------- final RMSNorm (writes d_out) ----------------
__global__ void rmsnorm_out(const float* __restrict__ x, const float* __restrict__ g,
                            float* __restrict__ outp) {
  int row = blockIdx.x * 4 + (threadIdx.x >> 6);
  int lane = threadIdx.x & 63;
  const float* xr = x + (size_t)row * DM + lane * 8;
  f32x4 a = *(const f32x4*)xr;
  f32x4 b = *(const f32x4*)(xr + 4);
  float ss = a[0]*a[0]+a[1]*a[1]+a[2]*a[2]+a[3]*a[3]+b[0]*b[0]+b[1]*b[1]+b[2]*b[2]+b[3]*b[3];
#pragma unroll
  for (int m = 1; m < 64; m <<= 1) ss += __shfl_xor(ss, m, 64);
  float sc = rsqrtf(ss * (1.0f / DM) + EPSV);
  const float* gp = g + lane * 8;
  float* o = outp + (size_t)row * DM + lane * 8;
  f32x4 o0, o1;
#pragma unroll
  for (int j = 0; j < 4; j++) { o0[j] = a[j] * sc * gp[j]; o1[j] = b[j] * sc * gp[4 + j]; }
  *(f32x4*)o = o0;
  *(f32x4*)(o + 4) = o1;
}

// ---------------- GEMM: out[M,N] = A[M,K] @ W[N,K]^T ----------------
// Statically unrolled 2-buffer pipeline, counted vmcnt, precomputed addresses.
// FUSE 1: residual += ; emit bf16 h; sumsq partials -> atomicAdd ssq_out.
// FUSE 2: qkv (rows scaled by rsqrt(ssq/512+eps)); cols>=1024 -> permuted V
//         transpose to vtb. FUSE 3: W13 interleaved -> silu(h1)*h3.
template<int AR, int AC, int FUSE>
__global__ __launch_bounds__(256) void gemm_bt(const short* __restrict__ A, const short* __restrict__ W,
                                               short* __restrict__ outb, float* __restrict__ outf,
                                               short* __restrict__ vtb,
                                               const float* __restrict__ ssq_in,
                                               float* __restrict__ ssq_out,
                                               short* __restrict__ hb, int N, int K) {
  constexpr int BM = AR * 32;
  constexpr int BN = AC * 32;
  constexpr int NA = BM / 64, NB = BN / 64;
  constexpr int LPS = NA + NB;
  __shared__ short As[2][BM * 32];
  __shared__ short Bs[2][BN * 32];
  const int tid = threadIdx.x;
  const int lane = tid & 63;
  const int w = tid >> 6;
  const int wr = w >> 1, wc = w & 1;
  const int qi = lane & 15, g = lane >> 4;
  const int m0 = blockIdx.x * BM, n0 = blockIdx.y * BN;

  const short* ap[NA];
  const short* wp[NB];
#pragma unroll
  for (int i = 0; i < NA; i++) {
    int s = i * 256 + tid;
    int row = s >> 2, gl = s & 3, gd = gl ^ ((row >> 1) & 3);
    ap[i] = A + (size_t)(m0 + row) * K + gd * 8;
  }
#pragma unroll
  for (int i = 0; i < NB; i++) {
    int s = i * 256 + tid;
    int row = s >> 2, gl = s & 3, gd = gl ^ ((row >> 1) & 3);
    wp[i] = W + (size_t)(n0 + row) * K + gd * 8;
  }
  int aro[AR], bro[AC];
#pragma unroll
  for (int i = 0; i < AR; i++) {
    int row = wr * AR * 16 + i * 16 + qi;
    aro[i] = row * 64 + ((g ^ ((row >> 1) & 3)) * 16);
  }
#pragma unroll
  for (int j = 0; j < AC; j++) {
    int row = wc * AC * 16 + j * 16 + qi;
    bro[j] = row * 64 + ((g ^ ((row >> 1) & 3)) * 16);
  }
  f32x4 acc[AR][AC] = {};

#define STAGE_G(BUF)                                                             \
  {                                                                              \
    _Pragma("unroll")                                                            \
    for (int i = 0; i < NA; i++) {                                               \
      GLLDS(ap[i], (char*)As[BUF] + (i * 256 + w * 64) * 16);                    \
      ap[i] += 32;                                                               \
    }                                                                            \
    _Pragma("unroll")                                                            \
    for (int i = 0; i < NB; i++) {                                               \
      GLLDS(wp[i], (char*)Bs[BUF] + (i * 256 + w * 64) * 16);                    \
      wp[i] += 32;                                                               \
    }                                                                            \
  }

#define BODY_G(BUF, T)                                                           \
  {                                                                              \
    s16x8 af[AR], bf[AC];                                                        \
    _Pragma("unroll")                                                            \
    for (int i = 0; i < AR; i++) af[i] = *(const s16x8*)((char*)As[BUF] + aro[i]); \
    _Pragma("unroll")                                                            \
    for (int j = 0; j < AC; j++) bf[j] = *(const s16x8*)((char*)Bs[BUF] + bro[j]); \
    asm volatile("s_waitcnt lgkmcnt(0)" ::: "memory");                           \
    __builtin_amdgcn_s_barrier();                                                \
    bool more = ((T) + 2 < nt);                                                  \
    if (more) STAGE_G(BUF);                                                      \
    _Pragma("unroll")                                                            \
    for (int i = 0; i < AR; i++)                                                 \
      _Pragma("unroll")                                                          \
      for (int j = 0; j < AC; j++)                                               \
        acc[i][j] = MFMA_BF16(af[i], bf[j], acc[i][j]);                          \
    if (more) asm volatile("s_waitcnt vmcnt(%0)" :: "n"(LPS) : "memory");        \
    else      asm volatile("s_waitcnt vmcnt(0)" ::: "memory");                   \
    __builtin_amdgcn_s_barrier();                                                \
  }

  const int nt = K >> 5;  // even (K = 512 or 2048)
  STAGE_G(0);
  STAGE_G(1);
  asm volatile("s_waitcnt vmcnt(%0)" :: "n"(LPS) : "memory");
  __builtin_amdgcn_s_barrier();
  for (int t = 0; t < nt; t += 2) {
    BODY_G(0, t);
    BODY_G(1, t + 1);
  }
#undef STAGE_G
#undef BODY_G

  float srow[AR][4];
  if (FUSE == 2 || FUSE == 3) {
#pragma unroll
    for (int i = 0; i < AR; i++) {
      int rbase = m0 + wr * AR * 16 + i * 16 + g * 4;
#pragma unroll
      for (int r = 0; r < 4; r++)
        srow[i][r] = rsqrtf(ssq_in[rbase + r] * (1.0f / DM) + EPSV);
    }
  }
  float part[AR][4];
  if (FUSE == 1) {
#pragma unroll
    for (int i = 0; i < AR; i++)
#pragma unroll
      for (int r = 0; r < 4; r++) part[i][r] = 0.f;
  }

#pragma unroll
  for (int i = 0; i < AR; i++) {
    int rbase = m0 + wr * AR * 16 + i * 16 + g * 4;
#pragma unroll
    for (int j = 0; j < AC; j++) {
      int col = n0 + wc * AC * 16 + j * 16 + qi;
      if (FUSE == 2 && col >= 1024) {
        // V transpose with sub-granule permutation: o = q32*8+h*4+g -> p = q32*8+g*2+h
        int bbv = rbase >> 10, s = rbase & 1023;
        int c = col - 1024, hhv = c >> 6, d = c & 63;
        int o = (s & 63) >> 2;
        int gg = o & 3, h2 = (o >> 2) & 1, q32 = o >> 3;
        int pnew = q32 * 8 + gg * 2 + h2;
        s16x4 o4;
#pragma unroll
        for (int r = 0; r < 4; r++) o4[r] = f2b(acc[i][j][r] * srow[i][r]);
        *(s16x4*)(vtb + (((size_t)(bbv * 8 + hhv) * 64 + d) << 10) + (s & ~63) + pnew * 4) = o4;
      } else if (FUSE == 3) {
#pragma unroll
        for (int r = 0; r < 4; r++) {
          float own = acc[i][j][r] * srow[i][r];
          float other = __shfl_xor(own, 1, 64);
          float sv = own / (1.0f + __expf(-own));
          if (!(lane & 1))
            outb[(size_t)(rbase + r) * (N >> 1) + (col >> 1)] = f2b(sv * other);
        }
      } else if (FUSE == 1) {
#pragma unroll
        for (int r = 0; r < 4; r++) {
          size_t idx = (size_t)(rbase + r) * N + col;
          float xnew = outf[idx] + acc[i][j][r];
          outf[idx] = xnew;
          hb[idx] = f2b(xnew);
          part[i][r] += xnew * xnew;
        }
      } else {
#pragma unroll
        for (int r = 0; r < 4; r++)
          outb[(size_t)(rbase + r) * N + col] = f2b(acc[i][j][r] * srow[i][r]);
      }
    }
  }
  if (FUSE == 1) {
#pragma unroll
    for (int i = 0; i < AR; i++) {
      int rbase = m0 + wr * AR * 16 + i * 16 + g * 4;
#pragma unroll
      for (int r = 0; r < 4; r++) {
        float p = part[i][r];
#pragma unroll
        for (int m = 1; m < 16; m <<= 1) p += __shfl_xor(p, m, 16);
        if (qi == 0) atomicAdd(&ssq_out[rbase + r], p);
      }
    }
  }
}

// ---------------- Flash attention: 4 waves x 16 q rows (QBLK=64), KVBLK=128 ----------------
__global__ __launch_bounds__(256) void attn_kernel(const short* __restrict__ qkv, const short* __restrict__ vt,
                                                   const int* __restrict__ ids, short* __restrict__ Ob) {
  const int bh = blockIdx.x;
  const int bb = bh >> 3, hh = bh & 7;
  const int q0 = blockIdx.y * 64;
  const int tid = threadIdx.x, lane = tid & 63, w = tid >> 6;
  const int g = lane >> 4, qi = lane & 15;
  __shared__ short Kl[2][128 * 64];   // [k][d], XOR-swizzled 16B granules
  __shared__ short Vl[2][64 * 128];   // [d][k-permuted], XOR-swizzled
  __shared__ int Kid[2][128];
  const short* kbase = qkv + 512 + hh * 64;
  const short* vbase = vt + (size_t)bh * 64 * SEQ;
  s16x8 qf0, qf1;
  {
    int qrow = q0 + w * 16 + qi;
    const short* qp = qkv + (size_t)(bb * SEQ + qrow) * 1536 + hh * 64 + g * 8;
    qf0 = *(const s16x8*)qp;
    qf1 = *(const s16x8*)(qp + 32);
  }
  int qid = 0;
  if (ids) qid = ids[bb * SEQ + q0 + w * 16 + qi];
  float m_ = -1e30f, l_ = 0.f;
  f32x4 oacc[4] = {};  // lane holds O[q'=g*4+r][d=dt*16+qi]

#define STAGE_ATTN(buf, ktt)                                                                     \
  {                                                                                              \
    _Pragma("unroll")                                                                            \
    for (int i = 0; i < 4; i++) {                                                                \
      int s = i * 256 + tid;                                                                     \
      int row = s >> 3, gl = s & 7, gd = gl ^ (row & 7);                                         \
      GLLDS(kbase + (size_t)(bb * SEQ + (ktt) + row) * 1536 + gd * 8,                            \
            (char*)Kl[buf] + (i * 256 + w * 64) * 16);                                           \
    }                                                                                            \
    _Pragma("unroll")                                                                            \
    for (int i = 0; i < 4; i++) {                                                                \
      int s = i * 256 + tid;                                                                     \
      int d = s >> 4, gl = s & 15, gd = gl ^ (d & 7);                                            \
      GLLDS(vbase + (size_t)d * SEQ + (ktt) + gd * 8, (char*)Vl[buf] + (i * 256 + w * 64) * 16); \
    }                                                                                            \
    if (ids && w < 2) GLLDS4(ids + bb * SEQ + (ktt) + w * 64 + lane, (char*)Kid[buf] + w * 256); \
  }

  STAGE_ATTN(0, 0);
  __syncthreads();
  int cur = 0;
  for (int kt = 0; kt < SEQ; kt += 128) {
    if (kt + 128 < SEQ) STAGE_ATTN(cur ^ 1, kt + 128);
    // QK^T swapped (log2 domain, log2e folded into Wq)
    f32x4 sc[8];
    __builtin_amdgcn_s_setprio(1);
#pragma unroll
    for (int kc = 0; kc < 8; kc++) {
      int krow = kc * 16 + qi;
      s16x8 kf0 = *(const s16x8*)(Kl[cur] + krow * 64 + ((g ^ (krow & 7)) * 8));
      s16x8 kf1 = *(const s16x8*)(Kl[cur] + krow * 64 + (((4 + g) ^ (krow & 7)) * 8));
      f32x4 s4 = {};
      s4 = MFMA_BF16(kf0, qf0, s4);
      s4 = MFMA_BF16(kf1, qf1, s4);
      sc[kc] = s4;
    }
    __builtin_amdgcn_s_setprio(0);
    float p[8][4];
#pragma unroll
    for (int kc = 0; kc < 8; kc++)
#pragma unroll
      for (int r = 0; r < 4; r++) p[kc][r] = sc[kc][r];
    if (ids) {
#pragma unroll
      for (int kc = 0; kc < 8; kc++) {
        int4 kid4 = *(const int4*)(Kid[cur] + kc * 16 + g * 4);
        if (kid4.x != qid) p[kc][0] = -1e30f;
        if (kid4.y != qid) p[kc][1] = -1e30f;
        if (kid4.z != qid) p[kc][2] = -1e30f;
        if (kid4.w != qid) p[kc][3] = -1e30f;
      }
    }
    float mx = fmaxf(fmaxf(p[0][0], p[0][1]), fmaxf(p[0][2], p[0][3]));
#pragma unroll
    for (int kc = 1; kc < 8; kc++)
      mx = fmaxf(mx, fmaxf(fmaxf(p[kc][0], p[kc][1]), fmaxf(p[kc][2], p[kc][3])));
    mx = fmaxf(mx, __shfl_xor(mx, 16, 64));
    mx = fmaxf(mx, __shfl_xor(mx, 32, 64));
    if (__any(mx > m_ + 8.f)) {   // defer-max
      float nm = fmaxf(m_, mx);
      float c = exp2f(m_ - nm);
      m_ = nm;
      l_ *= c;
#pragma unroll
      for (int r = 0; r < 4; r++) {
        float cr = __shfl(c, g * 4 + r, 16);
        oacc[0][r] *= cr; oacc[1][r] *= cr; oacc[2][r] *= cr; oacc[3][r] *= cr;
      }
    }
    float sum = 0.f;
#pragma unroll
    for (int kc = 0; kc < 8; kc++)
#pragma unroll
      for (int r = 0; r < 4; r++) {
        p[kc][r] = exp2f(p[kc][r] - m_);
        sum += p[kc][r];
      }
    sum += __shfl_xor(sum, 16, 64);
    sum += __shfl_xor(sum, 32, 64);
    l_ += sum;
    // PV: single b128 V fragments thanks to permuted vt layout
#pragma unroll
    for (int kk = 0; kk < 2; kk++) {
      s16x8 pa, pb;
#pragma unroll
      for (int r = 0; r < 4; r++) {
        pa[r] = f2b(p[kk * 4 + 0][r]); pa[4 + r] = f2b(p[kk * 4 + 1][r]);
        pb[r] = f2b(p[kk * 4 + 2][r]); pb[4 + r] = f2b(p[kk * 4 + 3][r]);
      }
      __builtin_amdgcn_s_setprio(1);
#pragma unroll
      for (int dt = 0; dt < 4; dt++) {
        int dl = dt * 16 + qi;
        const short* vr = Vl[cur] + dl * 128;
        s16x8 vf0 = *(const s16x8*)(vr + (kk * 8 + (g ^ (dl & 7))) * 8);
        s16x8 vf1 = *(const s16x8*)(vr + (kk * 8 + ((4 + g) ^ (dl & 7))) * 8);
        oacc[dt] = MFMA_BF16(pa, vf0, oacc[dt]);
        oacc[dt] = MFMA_BF16(pb, vf1, oacc[dt]);
      }
      __builtin_amdgcn_s_setprio(0);
    }
    __syncthreads();  // drains prefetch; all reads of [cur] done
    cur ^= 1;
  }
#undef STAGE_ATTN
  const size_t obase = (size_t)(bb * SEQ) * DM + hh * 64;
#pragma unroll
  for (int r = 0; r < 4; r++) {
    float lr = __shfl(l_, g * 4 + r, 16);
    float inv = 1.0f / lr;
    int q = q0 + w * 16 + g * 4 + r;
#pragma unroll
    for (int dt = 0; dt < 4; dt++)
      Ob[obase + (size_t)q * DM + dt * 16 + qi] = f2b(oacc[dt][r] * inv);
  }
}

// ---------------- host ----------------
extern "C" void kernel_launch(void* const* d_in, const int* in_sizes, int n_in,
                              void* d_out, int out_size, void* d_ws, size_t ws_size,
                              hipStream_t stream) {
  const float* x_in  = (const float*)d_in[0];
  const int* col_ids = (const int*)d_in[1];
  const int* row_ids = (const int*)d_in[2];
  const int* nbr_ids = (const int*)d_in[3];
  const float* g_attn = (const float*)d_in[11];
  const float* g_ffn  = (const float*)d_in[12];
  const float* g_out  = (const float*)d_in[13];

  char* ws = (char*)d_ws;
  float* x    = (float*)(ws);
  short* h    = (short*)(ws + (size_t)(8u  << 20));
  short* qkv  = (short*)(ws + (size_t)(12u << 20));
  short* vt   = (short*)(ws + (size_t)(24u << 20));
  short* ob   = (short*)(ws + (size_t)(28u << 20));
  float* sbuf = (float*)(ws + (size_t)(33u << 20));   // 21 slots x 4096 fp32
  short* fa   = (short*)(ws + (size_t)(44u << 20));
  short* wqkv = (short*)(ws + (size_t)(60u  << 20));  // [16][1536][512]
  short* wob  = (short*)(ws + (size_t)(84u  << 20));  // [16][512][512]
  short* w13  = (short*)(ws + (size_t)(92u  << 20));  // [4][4096][512] interleaved
  short* w2b  = (short*)(ws + (size_t)(108u << 20));  // [4][512][2048]

  cvt_all<<<dim3(1024, 7), 256, 0, stream>>>((const f32x4*)d_in[4], (const f32x4*)d_in[5],
                                             (const f32x4*)d_in[6], (const f32x4*)d_in[7],
                                             (const f32x4*)d_in[8], (const f32x4*)d_in[9],
                                             (const f32x4*)d_in[10], g_attn, g_ffn,
                                             wqkv, wob, w13, w2b);
  init_kernel<<<1024, 256, 0, stream>>>(x_in, x, h, sbuf);

  const int* idsarr[4] = {col_ids, row_ids, nbr_ids, nullptr};

  for (int l = 0; l < 4; l++) {
    for (int r = 0; r < 4; r++) {
      int slot = l * 5 + r;
      size_t woff = (size_t)(l * 4 + r) * 1536 * DM;
      gemm_bt<4, 2, 2><<<dim3(32, 24), 256, 0, stream>>>(h, wqkv + woff, qkv, nullptr, vt,
                                                         sbuf + (size_t)slot * 4096, nullptr,
                                                         nullptr, 1536, DM);
      attn_kernel<<<dim3(32, 16), 256, 0, stream>>>(qkv, vt, idsarr[r], ob);
      gemm_bt<2, 2, 1><<<dim3(64, 8), 256, 0, stream>>>(ob, wob + (size_t)(l * 4 + r) * DM * DM,
                                                        nullptr, x, nullptr, nullptr,
                                                        sbuf + (size_t)(slot + 1) * 4096, h, DM, DM);
    }
    int fslot = l * 5 + 4;
    gemm_bt<4, 2, 3><<<dim3(32, 64), 256, 0, stream>>>(h, w13 + (size_t)l * 4096 * DM, fa, nullptr,
                                                       nullptr, sbuf + (size_t)fslot * 4096,
                                                       nullptr, nullptr, 4096, DM);
    gemm_bt<2, 2, 1><<<dim3(64, 8), 256, 0, stream>>>(fa, w2b + (size_t)l * DM * 2048, nullptr, x,
                                                      nullptr, nullptr,
                                                      sbuf + (size_t)(fslot + 1) * 4096, h, DM, 2048);
  }
  rmsnorm_out<<<1024, 256, 0, stream>>>(x, g_out, (float*)d_out);
}

// Round 13
// 1130.912 us; speedup vs baseline: 1.1279x; 1.1279x over previous
//
#include <hip/hip_runtime.h>
#include <hip/hip_bf16.h>

// RelationalTransformer forward on MI355X (gfx950). Round 12 = exact R8 revert
// (session-best 1134us). R9/R10/R11 experiments (cvt vectorize-wider, QBLK=32,
// sparse-sort, nontemporal, setprio-in-lockstep-attn) all measured negative
// and are removed. Structure: gamma folded into weights at cvt; 1/rms applied
// in consumer-GEMM epilogues; residual GEMMs emit bf16 h + per-row sumsq
// (atomicAdd into per-norm slots); counted-vmcnt 2-deep GEMM pipeline;
// swapped-QK^T in-register-softmax flash attention, V pre-transposed+permuted
// by the QKV epilogue so PV B-fragments are single ds_read_b128.

typedef __attribute__((ext_vector_type(4))) float f32x4;
typedef __attribute__((ext_vector_type(8))) short s16x8;
typedef __attribute__((ext_vector_type(4))) short s16x4;

#define SEQ 1024
#define DM 512
#define MTOT 4096
#define EPSV 1.1920929e-07f
#define LOG2E 1.44269504088896f

static __device__ __forceinline__ float b2f(short s) {
  unsigned u = ((unsigned)(unsigned short)s) << 16;
  return __builtin_bit_cast(float, u);
}
static __device__ __forceinline__ short f2b(float f) {
  unsigned u = __builtin_bit_cast(unsigned, f);
  u = (u + 0x7fffu + ((u >> 16) & 1u)) >> 16;  // RNE; inputs never NaN
  return (short)(unsigned short)u;
}

#define MFMA_BF16(a, b, c) __builtin_amdgcn_mfma_f32_16x16x32_bf16((a), (b), (c), 0, 0, 0)
#define GLLDS(gp, lp)                                                                        \
  __builtin_amdgcn_global_load_lds((const __attribute__((address_space(1))) unsigned*)(gp),  \
                                   (__attribute__((address_space(3))) unsigned*)(lp), 16, 0, 0)
#define GLLDS4(gp, lp)                                                                       \
  __builtin_amdgcn_global_load_lds((const __attribute__((address_space(1))) unsigned*)(gp),  \
                                   (__attribute__((address_space(3))) unsigned*)(lp), 4, 0, 0)

// ---------------- merged weight conversion (one launch), gamma folded ----------------
// blockIdx.y: 0..2 = Wq/Wk/Wv -> wqkv (g_attn folded; q also *0.125*log2e);
// 3 = Wo -> wob; 4,5 = W1/W3 -> w13 interleaved (g_ffn folded); 6 = W2 -> w2b.
__global__ void cvt_all(const f32x4* __restrict__ wq, const f32x4* __restrict__ wk,
                        const f32x4* __restrict__ wv, const f32x4* __restrict__ wo,
                        const f32x4* __restrict__ w1, const f32x4* __restrict__ w3,
                        const f32x4* __restrict__ w2, const float* __restrict__ g_attn,
                        const float* __restrict__ g_ffn, s16x4* __restrict__ wqkv,
                        s16x4* __restrict__ wob, s16x4* __restrict__ w13,
                        s16x4* __restrict__ w2b) {
  int i = blockIdx.x * 256 + threadIdx.x;  // vec4 index < 1048576
  int which = blockIdx.y;
  s16x4 o;
  if (which < 3) {
    const f32x4* src = which == 0 ? wq : (which == 1 ? wk : wv);
    f32x4 v = src[i];
    int lr = i >> 16, k4 = i & 127, n = (i >> 7) & 511;
    const float* gp = g_attn + lr * 512 + k4 * 4;
    float sc = (which == 0) ? 0.125f * LOG2E : 1.0f;
#pragma unroll
    for (int j = 0; j < 4; j++) o[j] = f2b(v[j] * gp[j] * sc);
    wqkv[(size_t)lr * 196608 + (which * 512 + n) * 128 + k4] = o;
  } else if (which == 3) {
    f32x4 v = wo[i];
#pragma unroll
    for (int j = 0; j < 4; j++) o[j] = f2b(v[j]);
    wob[i] = o;
  } else if (which < 6) {
    const f32x4* src = which == 4 ? w1 : w3;
    int off = which - 4;
    f32x4 v = src[i];
    int l = i >> 18, n = (i >> 7) & 2047, k4 = i & 127;
    const float* gp = g_ffn + l * 512 + k4 * 4;
#pragma unroll
    for (int j = 0; j < 4; j++) o[j] = f2b(v[j] * gp[j]);
    w13[(size_t)l * 524288 + (n * 2 + off) * 128 + k4] = o;
  } else {
    f32x4 v = w2[i];
#pragma unroll
    for (int j = 0; j < 4; j++) o[j] = f2b(v[j]);
    w2b[i] = o;
  }
}

// ---------------- init: x copy + bf16 h + sumsq slot0 + zero slots 1..20 ----------------
__global__ void init_kernel(const float* __restrict__ xin, float* __restrict__ x,
                            short* __restrict__ h, float* __restrict__ sbuf) {
  int gid = blockIdx.x * 256 + threadIdx.x;
  if (gid < 20 * 4096) sbuf[4096 + gid] = 0.f;  // slots 1..20 (atomicAdd targets)
  int row = blockIdx.x * 4 + (threadIdx.x >> 6);
  int lane = threadIdx.x & 63;
  const float* xr = xin + (size_t)row * DM + lane * 8;
  f32x4 a = *(const f32x4*)xr;
  f32x4 b = *(const f32x4*)(xr + 4);
  float* xo = x + (size_t)row * DM + lane * 8;
  *(f32x4*)xo = a;
  *(f32x4*)(xo + 4) = b;
  s16x8 ho;
#pragma unroll
  for (int j = 0; j < 4; j++) { ho[j] = f2b(a[j]); ho[4 + j] = f2b(b[j]); }
  *(s16x8*)(h + (size_t)row * DM + lane * 8) = ho;
  float ss = a[0]*a[0]+a[1]*a[1]+a[2]*a[2]+a[3]*a[3]+b[0]*b[0]+b[1]*b[1]+b[2]*b[2]+b[3]*b[3];
#pragma unroll
  for (int m = 1; m < 64; m <<= 1) ss += __shfl_xor(ss, m, 64);
  if (lane == 0) sbuf[row] = ss;
}

// ---------------- final RMSNorm (self-contained, writes d_out) ----------------
__global__ void rmsnorm_out(const float* __restrict__ x, const float* __restrict__ g,
                            float* __restrict__ outp) {
  int row = blockIdx.x * 4 + (threadIdx.x >> 6);
  int lane = threadIdx.x & 63;
  const float* xr = x + (size_t)row * DM + lane * 8;
  f32x4 a = *(const f32x4*)xr;
  f32x4 b = *(const f32x4*)(xr + 4);
  float ss = a[0]*a[0]+a[1]*a[1]+a[2]*a[2]+a[3]*a[3]+b[0]*b[0]+b[1]*b[1]+b[2]*b[2]+b[3]*b[3];
#pragma unroll
  for (int m = 1; m < 64; m <<= 1) ss += __shfl_xor(ss, m, 64);
  float sc = rsqrtf(ss * (1.0f / DM) + EPSV);
  const float* gp = g + lane * 8;
  float* o = outp + (size_t)row * DM + lane * 8;
  f32x4 o0, o1;
#pragma unroll
  for (int j = 0; j < 4; j++) { o0[j] = a[j] * sc * gp[j]; o1[j] = b[j] * sc * gp[4 + j]; }
  *(f32x4*)o = o0;
  *(f32x4*)(o + 4) = o1;
}

// ---------------- GEMM: out[M,N] = A[M,K] @ W[N,K]^T ----------------
// Statically unrolled 2-buffer pipeline, counted vmcnt, precomputed addresses.
// FUSE 1: residual: xnew = outf[idx]+acc -> outf (fp32), hb (bf16), sumsq
//         partials -> atomicAdd ssq_out (next norm slot).
// FUSE 2: qkv: scale rows by s=rsqrt(ssq_in/512+eps); cols>=1024 -> permuted
//         V transpose to vtb, else bf16 out.
// FUSE 3: interleaved W13: scale rows by s, silu(h1)*h3 -> outb (stride N/2).
template<int AR, int AC, int FUSE>
__global__ __launch_bounds__(256) void gemm_bt(const short* __restrict__ A, const short* __restrict__ W,
                                               short* __restrict__ outb, float* __restrict__ outf,
                                               short* __restrict__ vtb,
                                               const float* __restrict__ ssq_in,
                                               float* __restrict__ ssq_out,
                                               short* __restrict__ hb, int N, int K) {
  constexpr int BM = AR * 32;
  constexpr int BN = AC * 32;
  constexpr int NA = BM / 64, NB = BN / 64;
  constexpr int LPS = NA + NB;
  __shared__ short As[2][BM * 32];
  __shared__ short Bs[2][BN * 32];
  const int tid = threadIdx.x;
  const int lane = tid & 63;
  const int w = tid >> 6;
  const int wr = w >> 1, wc = w & 1;
  const int qi = lane & 15, g = lane >> 4;
  const int m0 = blockIdx.x * BM, n0 = blockIdx.y * BN;

  const short* ap[NA];
  const short* wp[NB];
#pragma unroll
  for (int i = 0; i < NA; i++) {
    int s = i * 256 + tid;
    int row = s >> 2, gl = s & 3, gd = gl ^ ((row >> 1) & 3);
    ap[i] = A + (size_t)(m0 + row) * K + gd * 8;
  }
#pragma unroll
  for (int i = 0; i < NB; i++) {
    int s = i * 256 + tid;
    int row = s >> 2, gl = s & 3, gd = gl ^ ((row >> 1) & 3);
    wp[i] = W + (size_t)(n0 + row) * K + gd * 8;
  }
  int aro[AR], bro[AC];
#pragma unroll
  for (int i = 0; i < AR; i++) {
    int row = wr * AR * 16 + i * 16 + qi;
    aro[i] = row * 64 + ((g ^ ((row >> 1) & 3)) * 16);
  }
#pragma unroll
  for (int j = 0; j < AC; j++) {
    int row = wc * AC * 16 + j * 16 + qi;
    bro[j] = row * 64 + ((g ^ ((row >> 1) & 3)) * 16);
  }
  f32x4 acc[AR][AC] = {};

#define STAGE_G(BUF)                                                             \
  {                                                                              \
    _Pragma("unroll")                                                            \
    for (int i = 0; i < NA; i++) {                                               \
      GLLDS(ap[i], (char*)As[BUF] + (i * 256 + w * 64) * 16);                    \
      ap[i] += 32;                                                               \
    }                                                                            \
    _Pragma("unroll")                                                            \
    for (int i = 0; i < NB; i++) {                                               \
      GLLDS(wp[i], (char*)Bs[BUF] + (i * 256 + w * 64) * 16);                    \
      wp[i] += 32;                                                               \
    }                                                                            \
  }

#define BODY_G(BUF, T)                                                           \
  {                                                                              \
    s16x8 af[AR], bf[AC];                                                        \
    _Pragma("unroll")                                                            \
    for (int i = 0; i < AR; i++) af[i] = *(const s16x8*)((char*)As[BUF] + aro[i]); \
    _Pragma("unroll")                                                            \
    for (int j = 0; j < AC; j++) bf[j] = *(const s16x8*)((char*)Bs[BUF] + bro[j]); \
    asm volatile("s_waitcnt lgkmcnt(0)" ::: "memory");                           \
    __builtin_amdgcn_s_barrier();                                                \
    bool more = ((T) + 2 < nt);                                                  \
    if (more) STAGE_G(BUF);                                                      \
    _Pragma("unroll")                                                            \
    for (int i = 0; i < AR; i++)                                                 \
      _Pragma("unroll")                                                          \
      for (int j = 0; j < AC; j++)                                               \
        acc[i][j] = MFMA_BF16(af[i], bf[j], acc[i][j]);                          \
    if (more) asm volatile("s_waitcnt vmcnt(%0)" :: "n"(LPS) : "memory");        \
    else      asm volatile("s_waitcnt vmcnt(0)" ::: "memory");                   \
    __builtin_amdgcn_s_barrier();                                                \
  }

  const int nt = K >> 5;  // even (K = 512 or 2048)
  STAGE_G(0);
  STAGE_G(1);
  asm volatile("s_waitcnt vmcnt(%0)" :: "n"(LPS) : "memory");
  __builtin_amdgcn_s_barrier();
  for (int t = 0; t < nt; t += 2) {
    BODY_G(0, t);
    BODY_G(1, t + 1);
  }
#undef STAGE_G
#undef BODY_G

  // per-row 1/rms for FUSE2/FUSE3 (row = m0 + wr*AR*16 + i*16 + g*4 + r)
  float srow[AR][4];
  if (FUSE == 2 || FUSE == 3) {
#pragma unroll
    for (int i = 0; i < AR; i++) {
      int rbase = m0 + wr * AR * 16 + i * 16 + g * 4;
#pragma unroll
      for (int r = 0; r < 4; r++)
        srow[i][r] = rsqrtf(ssq_in[rbase + r] * (1.0f / DM) + EPSV);
    }
  }
  float part[AR][4];
  if (FUSE == 1) {
#pragma unroll
    for (int i = 0; i < AR; i++)
#pragma unroll
      for (int r = 0; r < 4; r++) part[i][r] = 0.f;
  }

#pragma unroll
  for (int i = 0; i < AR; i++) {
    int rbase = m0 + wr * AR * 16 + i * 16 + g * 4;
#pragma unroll
    for (int j = 0; j < AC; j++) {
      int col = n0 + wc * AC * 16 + j * 16 + qi;
      if (FUSE == 2 && col >= 1024) {
        // V transpose with sub-granule permutation: o = q32*8+h*4+g -> p = q32*8+g*2+h
        int bbv = rbase >> 10, s = rbase & 1023;
        int c = col - 1024, hhv = c >> 6, d = c & 63;
        int o = (s & 63) >> 2;
        int gg = o & 3, h2 = (o >> 2) & 1, q32 = o >> 3;
        int pnew = q32 * 8 + gg * 2 + h2;
        s16x4 o4;
#pragma unroll
        for (int r = 0; r < 4; r++) o4[r] = f2b(acc[i][j][r] * srow[i][r]);
        *(s16x4*)(vtb + (((size_t)(bbv * 8 + hhv) * 64 + d) << 10) + (s & ~63) + pnew * 4) = o4;
      } else if (FUSE == 3) {
#pragma unroll
        for (int r = 0; r < 4; r++) {
          float own = acc[i][j][r] * srow[i][r];
          float other = __shfl_xor(own, 1, 64);
          float sv = own / (1.0f + __expf(-own));
          if (!(lane & 1))
            outb[(size_t)(rbase + r) * (N >> 1) + (col >> 1)] = f2b(sv * other);
        }
      } else if (FUSE == 1) {
#pragma unroll
        for (int r = 0; r < 4; r++) {
          size_t idx = (size_t)(rbase + r) * N + col;
          float xnew = outf[idx] + acc[i][j][r];
          outf[idx] = xnew;
          hb[idx] = f2b(xnew);
          part[i][r] += xnew * xnew;
        }
      } else {
#pragma unroll
        for (int r = 0; r < 4; r++)
          outb[(size_t)(rbase + r) * N + col] = f2b(acc[i][j][r] * srow[i][r]);
      }
    }
  }
  if (FUSE == 1) {
#pragma unroll
    for (int i = 0; i < AR; i++) {
      int rbase = m0 + wr * AR * 16 + i * 16 + g * 4;
#pragma unroll
      for (int r = 0; r < 4; r++) {
        float p = part[i][r];
#pragma unroll
        for (int m = 1; m < 16; m <<= 1) p += __shfl_xor(p, m, 16);
        if (qi == 0) atomicAdd(&ssq_out[rbase + r], p);
      }
    }
  }
}

// ---------------- Flash attention: 4 waves x 16 q rows (QBLK=64), KVBLK=128 ----------------
__global__ __launch_bounds__(256) void attn_kernel(const short* __restrict__ qkv, const short* __restrict__ vt,
                                                   const int* __restrict__ ids, short* __restrict__ Ob) {
  const int bh = blockIdx.x;
  const int bb = bh >> 3, hh = bh & 7;
  const int q0 = blockIdx.y * 64;
  const int tid = threadIdx.x, lane = tid & 63, w = tid >> 6;
  const int g = lane >> 4, qi = lane & 15;
  __shared__ short Kl[2][128 * 64];   // [k][d], XOR-swizzled 16B granules
  __shared__ short Vl[2][64 * 128];   // [d][k-permuted], XOR-swizzled
  __shared__ int Kid[2][128];
  const short* kbase = qkv + 512 + hh * 64;
  const short* vbase = vt + (size_t)bh * 64 * SEQ;
  s16x8 qf0, qf1;
  {
    int qrow = q0 + w * 16 + qi;
    const short* qp = qkv + (size_t)(bb * SEQ + qrow) * 1536 + hh * 64 + g * 8;
    qf0 = *(const s16x8*)qp;
    qf1 = *(const s16x8*)(qp + 32);
  }
  int qid = 0;
  if (ids) qid = ids[bb * SEQ + q0 + w * 16 + qi];
  float m_ = -1e30f, l_ = 0.f;
  f32x4 oacc[4] = {};  // lane holds O[q'=g*4+r][d=dt*16+qi]

#define STAGE_ATTN(buf, ktt)                                                                     \
  {                                                                                              \
    _Pragma("unroll")                                                                            \
    for (int i = 0; i < 4; i++) {                                                                \
      int s = i * 256 + tid;                                                                     \
      int row = s >> 3, gl = s & 7, gd = gl ^ (row & 7);                                         \
      GLLDS(kbase + (size_t)(bb * SEQ + (ktt) + row) * 1536 + gd * 8,                            \
            (char*)Kl[buf] + (i * 256 + w * 64) * 16);                                           \
    }                                                                                            \
    _Pragma("unroll")                                                                            \
    for (int i = 0; i < 4; i++) {                                                                \
      int s = i * 256 + tid;                                                                     \
      int d = s >> 4, gl = s & 15, gd = gl ^ (d & 7);                                            \
      GLLDS(vbase + (size_t)d * SEQ + (ktt) + gd * 8, (char*)Vl[buf] + (i * 256 + w * 64) * 16); \
    }                                                                                            \
    if (ids && w < 2) GLLDS4(ids + bb * SEQ + (ktt) + w * 64 + lane, (char*)Kid[buf] + w * 256); \
  }

  STAGE_ATTN(0, 0);
  __syncthreads();
  int cur = 0;
  for (int kt = 0; kt < SEQ; kt += 128) {
    if (kt + 128 < SEQ) STAGE_ATTN(cur ^ 1, kt + 128);
    // QK^T swapped (log2 domain, log2e folded into Wq)
    f32x4 sc[8];
#pragma unroll
    for (int kc = 0; kc < 8; kc++) {
      int krow = kc * 16 + qi;
      s16x8 kf0 = *(const s16x8*)(Kl[cur] + krow * 64 + ((g ^ (krow & 7)) * 8));
      s16x8 kf1 = *(const s16x8*)(Kl[cur] + krow * 64 + (((4 + g) ^ (krow & 7)) * 8));
      f32x4 s4 = {};
      s4 = MFMA_BF16(kf0, qf0, s4);
      s4 = MFMA_BF16(kf1, qf1, s4);
      sc[kc] = s4;
    }
    float p[8][4];
#pragma unroll
    for (int kc = 0; kc < 8; kc++)
#pragma unroll
      for (int r = 0; r < 4; r++) p[kc][r] = sc[kc][r];
    if (ids) {
#pragma unroll
      for (int kc = 0; kc < 8; kc++) {
        int4 kid4 = *(const int4*)(Kid[cur] + kc * 16 + g * 4);
        if (kid4.x != qid) p[kc][0] = -1e30f;
        if (kid4.y != qid) p[kc][1] = -1e30f;
        if (kid4.z != qid) p[kc][2] = -1e30f;
        if (kid4.w != qid) p[kc][3] = -1e30f;
      }
    }
    float mx = fmaxf(fmaxf(p[0][0], p[0][1]), fmaxf(p[0][2], p[0][3]));
#pragma unroll
    for (int kc = 1; kc < 8; kc++)
      mx = fmaxf(mx, fmaxf(fmaxf(p[kc][0], p[kc][1]), fmaxf(p[kc][2], p[kc][3])));
    mx = fmaxf(mx, __shfl_xor(mx, 16, 64));
    mx = fmaxf(mx, __shfl_xor(mx, 32, 64));
    if (__any(mx > m_ + 8.f)) {   // defer-max
      float nm = fmaxf(m_, mx);
      float c = exp2f(m_ - nm);
      m_ = nm;
      l_ *= c;
#pragma unroll
      for (int r = 0; r < 4; r++) {
        float cr = __shfl(c, g * 4 + r, 16);
        oacc[0][r] *= cr; oacc[1][r] *= cr; oacc[2][r] *= cr; oacc[3][r] *= cr;
      }
    }
    float sum = 0.f;
#pragma unroll
    for (int kc = 0; kc < 8; kc++)
#pragma unroll
      for (int r = 0; r < 4; r++) {
        p[kc][r] = exp2f(p[kc][r] - m_);
        sum += p[kc][r];
      }
    sum += __shfl_xor(sum, 16, 64);
    sum += __shfl_xor(sum, 32, 64);
    l_ += sum;
    // PV: single b128 V fragments thanks to permuted vt layout
#pragma unroll
    for (int kk = 0; kk < 2; kk++) {
      s16x8 pa, pb;
#pragma unroll
      for (int r = 0; r < 4; r++) {
        pa[r] = f2b(p[kk * 4 + 0][r]); pa[4 + r] = f2b(p[kk * 4 + 1][r]);
        pb[r] = f2b(p[kk * 4 + 2][r]); pb[4 + r] = f2b(p[kk * 4 + 3][r]);
      }
#pragma unroll
      for (int dt = 0; dt < 4; dt++) {
        int dl = dt * 16 + qi;
        const short* vr = Vl[cur] + dl * 128;
        s16x8 vf0 = *(const s16x8*)(vr + (kk * 8 + (g ^ (dl & 7))) * 8);
        s16x8 vf1 = *(const s16x8*)(vr + (kk * 8 + ((4 + g) ^ (dl & 7))) * 8);
        oacc[dt] = MFMA_BF16(pa, vf0, oacc[dt]);
        oacc[dt] = MFMA_BF16(pb, vf1, oacc[dt]);
      }
    }
    __syncthreads();  // drains prefetch; all reads of [cur] done
    cur ^= 1;
  }
#undef STAGE_ATTN
  const size_t obase = (size_t)(bb * SEQ) * DM + hh * 64;
#pragma unroll
  for (int r = 0; r < 4; r++) {
    float lr = __shfl(l_, g * 4 + r, 16);
    float inv = 1.0f / lr;
    int q = q0 + w * 16 + g * 4 + r;
#pragma unroll
    for (int dt = 0; dt < 4; dt++)
      Ob[obase + (size_t)q * DM + dt * 16 + qi] = f2b(oacc[dt][r] * inv);
  }
}

// ---------------- host ----------------
extern "C" void kernel_launch(void* const* d_in, const int* in_sizes, int n_in,
                              void* d_out, int out_size, void* d_ws, size_t ws_size,
                              hipStream_t stream) {
  const float* x_in  = (const float*)d_in[0];
  const int* col_ids = (const int*)d_in[1];
  const int* row_ids = (const int*)d_in[2];
  const int* nbr_ids = (const int*)d_in[3];
  const float* g_attn = (const float*)d_in[11];
  const float* g_ffn  = (const float*)d_in[12];
  const float* g_out  = (const float*)d_in[13];

  char* ws = (char*)d_ws;
  float* x    = (float*)(ws);
  short* h    = (short*)(ws + (size_t)(8u  << 20));
  short* qkv  = (short*)(ws + (size_t)(12u << 20));
  short* vt   = (short*)(ws + (size_t)(24u << 20));
  short* ob   = (short*)(ws + (size_t)(28u << 20));
  float* sbuf = (float*)(ws + (size_t)(33u << 20));   // 21 slots x 4096 fp32
  short* fa   = (short*)(ws + (size_t)(44u << 20));
  short* wqkv = (short*)(ws + (size_t)(60u  << 20));  // [16][1536][512]
  short* wob  = (short*)(ws + (size_t)(84u  << 20));  // [16][512][512]
  short* w13  = (short*)(ws + (size_t)(92u  << 20));  // [4][4096][512] interleaved
  short* w2b  = (short*)(ws + (size_t)(108u << 20));  // [4][512][2048]

  cvt_all<<<dim3(4096, 7), 256, 0, stream>>>((const f32x4*)d_in[4], (const f32x4*)d_in[5],
                                             (const f32x4*)d_in[6], (const f32x4*)d_in[7],
                                             (const f32x4*)d_in[8], (const f32x4*)d_in[9],
                                             (const f32x4*)d_in[10], g_attn, g_ffn,
                                             (s16x4*)wqkv, (s16x4*)wob, (s16x4*)w13, (s16x4*)w2b);
  init_kernel<<<1024, 256, 0, stream>>>(x_in, x, h, sbuf);

  const int* idsarr[4] = {col_ids, row_ids, nbr_ids, nullptr};

  for (int l = 0; l < 4; l++) {
    for (int r = 0; r < 4; r++) {
      int slot = l * 5 + r;
      size_t woff = (size_t)(l * 4 + r) * 1536 * DM;
      gemm_bt<4, 2, 2><<<dim3(32, 24), 256, 0, stream>>>(h, wqkv + woff, qkv, nullptr, vt,
                                                         sbuf + (size_t)slot * 4096, nullptr,
                                                         nullptr, 1536, DM);
      attn_kernel<<<dim3(32, 16), 256, 0, stream>>>(qkv, vt, idsarr[r], ob);
      gemm_bt<2, 2, 1><<<dim3(64, 8), 256, 0, stream>>>(ob, wob + (size_t)(l * 4 + r) * DM * DM,
                                                        nullptr, x, nullptr, nullptr,
                                                        sbuf + (size_t)(slot + 1) * 4096, h, DM, DM);
    }
    int fslot = l * 5 + 4;
    gemm_bt<4, 2, 3><<<dim3(32, 64), 256, 0, stream>>>(h, w13 + (size_t)l * 4096 * DM, fa, nullptr,
                                                       nullptr, sbuf + (size_t)fslot * 4096,
                                                       nullptr, nullptr, 4096, DM);
    gemm_bt<2, 2, 1><<<dim3(64, 8), 256, 0, stream>>>(fa, w2b + (size_t)l * DM * 2048, nullptr, x,
                                                      nullptr, nullptr,
                                                      sbuf + (size_t)(fslot + 1) * 4096, h, DM, 2048);
  }
  rmsnorm_out<<<1024, 256, 0, stream>>>(x, g_out, (float*)d_out);
}

// Round 14
// 1099.968 us; speedup vs baseline: 1.1596x; 1.0281x over previous
//
#include <hip/hip_runtime.h>
#include <hip/hip_bf16.h>

// RelationalTransformer forward on MI355X (gfx950). Round 13 = R12 (session
// best 1131us) + v_cvt_pk_bf16_f32 packing in the attn P->bf16 pack (replaces
// ~130 integer VALU ops per k-tile with 16 cvt_pk) and in the FUSE2 V-write
// epilogue; init_kernel merged into cvt_all (one fewer dispatch).

typedef __attribute__((ext_vector_type(4))) float f32x4;
typedef __attribute__((ext_vector_type(8))) short s16x8;
typedef __attribute__((ext_vector_type(4))) short s16x4;
typedef __attribute__((ext_vector_type(4))) unsigned u32x4;
typedef __attribute__((ext_vector_type(2))) unsigned u32x2;

#define SEQ 1024
#define DM 512
#define MTOT 4096
#define EPSV 1.1920929e-07f
#define LOG2E 1.44269504088896f

static __device__ __forceinline__ float b2f(short s) {
  unsigned u = ((unsigned)(unsigned short)s) << 16;
  return __builtin_bit_cast(float, u);
}
static __device__ __forceinline__ short f2b(float f) {
  unsigned u = __builtin_bit_cast(unsigned, f);
  u = (u + 0x7fffu + ((u >> 16) & 1u)) >> 16;  // RNE; inputs never NaN
  return (short)(unsigned short)u;
}
// packed 2x f32 -> 2x bf16 (RNE), single instruction
static __device__ __forceinline__ unsigned cvtpk(float lo, float hi) {
  unsigned r;
  asm("v_cvt_pk_bf16_f32 %0, %1, %2" : "=v"(r) : "v"(lo), "v"(hi));
  return r;
}

#define MFMA_BF16(a, b, c) __builtin_amdgcn_mfma_f32_16x16x32_bf16((a), (b), (c), 0, 0, 0)
#define GLLDS(gp, lp)                                                                        \
  __builtin_amdgcn_global_load_lds((const __attribute__((address_space(1))) unsigned*)(gp),  \
                                   (__attribute__((address_space(3))) unsigned*)(lp), 16, 0, 0)
#define GLLDS4(gp, lp)                                                                       \
  __builtin_amdgcn_global_load_lds((const __attribute__((address_space(1))) unsigned*)(gp),  \
                                   (__attribute__((address_space(3))) unsigned*)(lp), 4, 0, 0)

// ---------------- merged weight conversion + init (one launch) ----------------
// blockIdx.y: 0..2 = Wq/Wk/Wv -> wqkv (g_attn folded; q also *0.125*log2e);
// 3 = Wo -> wob; 4,5 = W1/W3 -> w13 interleaved (g_ffn folded); 6 = W2 -> w2b;
// 7 (blocks <1024) = init: x copy + bf16 h + sumsq slot0 + zero slots 1..20.
__global__ void cvt_all(const f32x4* __restrict__ wq, const f32x4* __restrict__ wk,
                        const f32x4* __restrict__ wv, const f32x4* __restrict__ wo,
                        const f32x4* __restrict__ w1, const f32x4* __restrict__ w3,
                        const f32x4* __restrict__ w2, const float* __restrict__ g_attn,
                        const float* __restrict__ g_ffn, s16x4* __restrict__ wqkv,
                        s16x4* __restrict__ wob, s16x4* __restrict__ w13,
                        s16x4* __restrict__ w2b, const float* __restrict__ xin,
                        float* __restrict__ x, short* __restrict__ h,
                        float* __restrict__ sbuf) {
  int i = blockIdx.x * 256 + threadIdx.x;  // vec4 index < 1048576
  int which = blockIdx.y;
  s16x4 o;
  if (which < 3) {
    const f32x4* src = which == 0 ? wq : (which == 1 ? wk : wv);
    f32x4 v = src[i];
    int lr = i >> 16, k4 = i & 127, n = (i >> 7) & 511;
    const float* gp = g_attn + lr * 512 + k4 * 4;
    float sc = (which == 0) ? 0.125f * LOG2E : 1.0f;
#pragma unroll
    for (int j = 0; j < 4; j++) o[j] = f2b(v[j] * gp[j] * sc);
    wqkv[(size_t)lr * 196608 + (which * 512 + n) * 128 + k4] = o;
  } else if (which == 3) {
    f32x4 v = wo[i];
#pragma unroll
    for (int j = 0; j < 4; j++) o[j] = f2b(v[j]);
    wob[i] = o;
  } else if (which < 6) {
    const f32x4* src = which == 4 ? w1 : w3;
    int off = which - 4;
    f32x4 v = src[i];
    int l = i >> 18, n = (i >> 7) & 2047, k4 = i & 127;
    const float* gp = g_ffn + l * 512 + k4 * 4;
#pragma unroll
    for (int j = 0; j < 4; j++) o[j] = f2b(v[j] * gp[j]);
    w13[(size_t)l * 524288 + (n * 2 + off) * 128 + k4] = o;
  } else if (which == 6) {
    f32x4 v = w2[i];
#pragma unroll
    for (int j = 0; j < 4; j++) o[j] = f2b(v[j]);
    w2b[i] = o;
  } else {
    if (blockIdx.x >= 1024) return;
    int gid = blockIdx.x * 256 + threadIdx.x;
    if (gid < 20 * 4096) sbuf[4096 + gid] = 0.f;  // slots 1..20 (atomicAdd targets)
    int row = blockIdx.x * 4 + (threadIdx.x >> 6);
    int lane = threadIdx.x & 63;
    const float* xr = xin + (size_t)row * DM + lane * 8;
    f32x4 a = *(const f32x4*)xr;
    f32x4 b = *(const f32x4*)(xr + 4);
    float* xo = x + (size_t)row * DM + lane * 8;
    *(f32x4*)xo = a;
    *(f32x4*)(xo + 4) = b;
    s16x8 ho;
#pragma unroll
    for (int j = 0; j < 4; j++) { ho[j] = f2b(a[j]); ho[4 + j] = f2b(b[j]); }
    *(s16x8*)(h + (size_t)row * DM + lane * 8) = ho;
    float ss = a[0]*a[0]+a[1]*a[1]+a[2]*a[2]+a[3]*a[3]+b[0]*b[0]+b[1]*b[1]+b[2]*b[2]+b[3]*b[3];
#pragma unroll
    for (int m = 1; m < 64; m <<= 1) ss += __shfl_xor(ss, m, 64);
    if (lane == 0) sbuf[row] = ss;
  }
}

// ---------------- final RMSNorm (self-contained, writes d_out) ----------------
__global__ void rmsnorm_out(const float* __restrict__ x, const float* __restrict__ g,
                            float* __restrict__ outp) {
  int row = blockIdx.x * 4 + (threadIdx.x >> 6);
  int lane = threadIdx.x & 63;
  const float* xr = x + (size_t)row * DM + lane * 8;
  f32x4 a = *(const f32x4*)xr;
  f32x4 b = *(const f32x4*)(xr + 4);
  float ss = a[0]*a[0]+a[1]*a[1]+a[2]*a[2]+a[3]*a[3]+b[0]*b[0]+b[1]*b[1]+b[2]*b[2]+b[3]*b[3];
#pragma unroll
  for (int m = 1; m < 64; m <<= 1) ss += __shfl_xor(ss, m, 64);
  float sc = rsqrtf(ss * (1.0f / DM) + EPSV);
  const float* gp = g + lane * 8;
  float* o = outp + (size_t)row * DM + lane * 8;
  f32x4 o0, o1;
#pragma unroll
  for (int j = 0; j < 4; j++) { o0[j] = a[j] * sc * gp[j]; o1[j] = b[j] * sc * gp[4 + j]; }
  *(f32x4*)o = o0;
  *(f32x4*)(o + 4) = o1;
}

// ---------------- GEMM: out[M,N] = A[M,K] @ W[N,K]^T ----------------
// Statically unrolled 2-buffer pipeline, counted vmcnt, precomputed addresses.
// FUSE 1: residual: xnew = outf[idx]+acc -> outf (fp32), hb (bf16), sumsq
//         partials -> atomicAdd ssq_out (next norm slot).
// FUSE 2: qkv: scale rows by s=rsqrt(ssq_in/512+eps); cols>=1024 -> permuted
//         V transpose to vtb, else bf16 out.
// FUSE 3: interleaved W13: scale rows by s, silu(h1)*h3 -> outb (stride N/2).
template<int AR, int AC, int FUSE>
__global__ __launch_bounds__(256) void gemm_bt(const short* __restrict__ A, const short* __restrict__ W,
                                               short* __restrict__ outb, float* __restrict__ outf,
                                               short* __restrict__ vtb,
                                               const float* __restrict__ ssq_in,
                                               float* __restrict__ ssq_out,
                                               short* __restrict__ hb, int N, int K) {
  constexpr int BM = AR * 32;
  constexpr int BN = AC * 32;
  constexpr int NA = BM / 64, NB = BN / 64;
  constexpr int LPS = NA + NB;
  __shared__ short As[2][BM * 32];
  __shared__ short Bs[2][BN * 32];
  const int tid = threadIdx.x;
  const int lane = tid & 63;
  const int w = tid >> 6;
  const int wr = w >> 1, wc = w & 1;
  const int qi = lane & 15, g = lane >> 4;
  const int m0 = blockIdx.x * BM, n0 = blockIdx.y * BN;

  const short* ap[NA];
  const short* wp[NB];
#pragma unroll
  for (int i = 0; i < NA; i++) {
    int s = i * 256 + tid;
    int row = s >> 2, gl = s & 3, gd = gl ^ ((row >> 1) & 3);
    ap[i] = A + (size_t)(m0 + row) * K + gd * 8;
  }
#pragma unroll
  for (int i = 0; i < NB; i++) {
    int s = i * 256 + tid;
    int row = s >> 2, gl = s & 3, gd = gl ^ ((row >> 1) & 3);
    wp[i] = W + (size_t)(n0 + row) * K + gd * 8;
  }
  int aro[AR], bro[AC];
#pragma unroll
  for (int i = 0; i < AR; i++) {
    int row = wr * AR * 16 + i * 16 + qi;
    aro[i] = row * 64 + ((g ^ ((row >> 1) & 3)) * 16);
  }
#pragma unroll
  for (int j = 0; j < AC; j++) {
    int row = wc * AC * 16 + j * 16 + qi;
    bro[j] = row * 64 + ((g ^ ((row >> 1) & 3)) * 16);
  }
  f32x4 acc[AR][AC] = {};

#define STAGE_G(BUF)                                                             \
  {                                                                              \
    _Pragma("unroll")                                                            \
    for (int i = 0; i < NA; i++) {                                               \
      GLLDS(ap[i], (char*)As[BUF] + (i * 256 + w * 64) * 16);                    \
      ap[i] += 32;                                                               \
    }                                                                            \
    _Pragma("unroll")                                                            \
    for (int i = 0; i < NB; i++) {                                               \
      GLLDS(wp[i], (char*)Bs[BUF] + (i * 256 + w * 64) * 16);                    \
      wp[i] += 32;                                                               \
    }                                                                            \
  }

#define BODY_G(BUF, T)                                                           \
  {                                                                              \
    s16x8 af[AR], bf[AC];                                                        \
    _Pragma("unroll")                                                            \
    for (int i = 0; i < AR; i++) af[i] = *(const s16x8*)((char*)As[BUF] + aro[i]); \
    _Pragma("unroll")                                                            \
    for (int j = 0; j < AC; j++) bf[j] = *(const s16x8*)((char*)Bs[BUF] + bro[j]); \
    asm volatile("s_waitcnt lgkmcnt(0)" ::: "memory");                           \
    __builtin_amdgcn_s_barrier();                                                \
    bool more = ((T) + 2 < nt);                                                  \
    if (more) STAGE_G(BUF);                                                      \
    _Pragma("unroll")                                                            \
    for (int i = 0; i < AR; i++)                                                 \
      _Pragma("unroll")                                                          \
      for (int j = 0; j < AC; j++)                                               \
        acc[i][j] = MFMA_BF16(af[i], bf[j], acc[i][j]);                          \
    if (more) asm volatile("s_waitcnt vmcnt(%0)" :: "n"(LPS) : "memory");        \
    else      asm volatile("s_waitcnt vmcnt(0)" ::: "memory");                   \
    __builtin_amdgcn_s_barrier();                                                \
  }

  const int nt = K >> 5;  // even (K = 512 or 2048)
  STAGE_G(0);
  STAGE_G(1);
  asm volatile("s_waitcnt vmcnt(%0)" :: "n"(LPS) : "memory");
  __builtin_amdgcn_s_barrier();
  for (int t = 0; t < nt; t += 2) {
    BODY_G(0, t);
    BODY_G(1, t + 1);
  }
#undef STAGE_G
#undef BODY_G

  // per-row 1/rms for FUSE2/FUSE3 (row = m0 + wr*AR*16 + i*16 + g*4 + r)
  float srow[AR][4];
  if (FUSE == 2 || FUSE == 3) {
#pragma unroll
    for (int i = 0; i < AR; i++) {
      int rbase = m0 + wr * AR * 16 + i * 16 + g * 4;
#pragma unroll
      for (int r = 0; r < 4; r++)
        srow[i][r] = rsqrtf(ssq_in[rbase + r] * (1.0f / DM) + EPSV);
    }
  }
  float part[AR][4];
  if (FUSE == 1) {
#pragma unroll
    for (int i = 0; i < AR; i++)
#pragma unroll
      for (int r = 0; r < 4; r++) part[i][r] = 0.f;
  }

#pragma unroll
  for (int i = 0; i < AR; i++) {
    int rbase = m0 + wr * AR * 16 + i * 16 + g * 4;
#pragma unroll
    for (int j = 0; j < AC; j++) {
      int col = n0 + wc * AC * 16 + j * 16 + qi;
      if (FUSE == 2 && col >= 1024) {
        // V transpose with sub-granule permutation: o = q32*8+h*4+g -> p = q32*8+g*2+h
        int bbv = rbase >> 10, s = rbase & 1023;
        int c = col - 1024, hhv = c >> 6, d = c & 63;
        int o = (s & 63) >> 2;
        int gg = o & 3, h2 = (o >> 2) & 1, q32 = o >> 3;
        int pnew = q32 * 8 + gg * 2 + h2;
        u32x2 ov;
        ov[0] = cvtpk(acc[i][j][0] * srow[i][0], acc[i][j][1] * srow[i][1]);
        ov[1] = cvtpk(acc[i][j][2] * srow[i][2], acc[i][j][3] * srow[i][3]);
        *(s16x4*)(vtb + (((size_t)(bbv * 8 + hhv) * 64 + d) << 10) + (s & ~63) + pnew * 4) =
            __builtin_bit_cast(s16x4, ov);
      } else if (FUSE == 3) {
#pragma unroll
        for (int r = 0; r < 4; r++) {
          float own = acc[i][j][r] * srow[i][r];
          float other = __shfl_xor(own, 1, 64);
          float sv = own / (1.0f + __expf(-own));
          if (!(lane & 1))
            outb[(size_t)(rbase + r) * (N >> 1) + (col >> 1)] = f2b(sv * other);
        }
      } else if (FUSE == 1) {
#pragma unroll
        for (int r = 0; r < 4; r++) {
          size_t idx = (size_t)(rbase + r) * N + col;
          float xnew = outf[idx] + acc[i][j][r];
          outf[idx] = xnew;
          hb[idx] = f2b(xnew);
          part[i][r] += xnew * xnew;
        }
      } else {
#pragma unroll
        for (int r = 0; r < 4; r++)
          outb[(size_t)(rbase + r) * N + col] = f2b(acc[i][j][r] * srow[i][r]);
      }
    }
  }
  if (FUSE == 1) {
#pragma unroll
    for (int i = 0; i < AR; i++) {
      int rbase = m0 + wr * AR * 16 + i * 16 + g * 4;
#pragma unroll
      for (int r = 0; r < 4; r++) {
        float p = part[i][r];
#pragma unroll
        for (int m = 1; m < 16; m <<= 1) p += __shfl_xor(p, m, 16);
        if (qi == 0) atomicAdd(&ssq_out[rbase + r], p);
      }
    }
  }
}

// ---------------- Flash attention: 4 waves x 16 q rows (QBLK=64), KVBLK=128 ----------------
__global__ __launch_bounds__(256) void attn_kernel(const short* __restrict__ qkv, const short* __restrict__ vt,
                                                   const int* __restrict__ ids, short* __restrict__ Ob) {
  const int bh = blockIdx.x;
  const int bb = bh >> 3, hh = bh & 7;
  const int q0 = blockIdx.y * 64;
  const int tid = threadIdx.x, lane = tid & 63, w = tid >> 6;
  const int g = lane >> 4, qi = lane & 15;
  __shared__ short Kl[2][128 * 64];   // [k][d], XOR-swizzled 16B granules
  __shared__ short Vl[2][64 * 128];   // [d][k-permuted], XOR-swizzled
  __shared__ int Kid[2][128];
  const short* kbase = qkv + 512 + hh * 64;
  const short* vbase = vt + (size_t)bh * 64 * SEQ;
  s16x8 qf0, qf1;
  {
    int qrow = q0 + w * 16 + qi;
    const short* qp = qkv + (size_t)(bb * SEQ + qrow) * 1536 + hh * 64 + g * 8;
    qf0 = *(const s16x8*)qp;
    qf1 = *(const s16x8*)(qp + 32);
  }
  int qid = 0;
  if (ids) qid = ids[bb * SEQ + q0 + w * 16 + qi];
  float m_ = -1e30f, l_ = 0.f;
  f32x4 oacc[4] = {};  // lane holds O[q'=g*4+r][d=dt*16+qi]

#define STAGE_ATTN(buf, ktt)                                                                     \
  {                                                                                              \
    _Pragma("unroll")                                                                            \
    for (int i = 0; i < 4; i++) {                                                                \
      int s = i * 256 + tid;                                                                     \
      int row = s >> 3, gl = s & 7, gd = gl ^ (row & 7);                                         \
      GLLDS(kbase + (size_t)(bb * SEQ + (ktt) + row) * 1536 + gd * 8,                            \
            (char*)Kl[buf] + (i * 256 + w * 64) * 16);                                           \
    }                                                                                            \
    _Pragma("unroll")                                                                            \
    for (int i = 0; i < 4; i++) {                                                                \
      int s = i * 256 + tid;                                                                     \
      int d = s >> 4, gl = s & 15, gd = gl ^ (d & 7);                                            \
      GLLDS(vbase + (size_t)d * SEQ + (ktt) + gd * 8, (char*)Vl[buf] + (i * 256 + w * 64) * 16); \
    }                                                                                            \
    if (ids && w < 2) GLLDS4(ids + bb * SEQ + (ktt) + w * 64 + lane, (char*)Kid[buf] + w * 256); \
  }

  STAGE_ATTN(0, 0);
  __syncthreads();
  int cur = 0;
  for (int kt = 0; kt < SEQ; kt += 128) {
    if (kt + 128 < SEQ) STAGE_ATTN(cur ^ 1, kt + 128);
    // QK^T swapped (log2 domain, log2e folded into Wq)
    f32x4 sc[8];
#pragma unroll
    for (int kc = 0; kc < 8; kc++) {
      int krow = kc * 16 + qi;
      s16x8 kf0 = *(const s16x8*)(Kl[cur] + krow * 64 + ((g ^ (krow & 7)) * 8));
      s16x8 kf1 = *(const s16x8*)(Kl[cur] + krow * 64 + (((4 + g) ^ (krow & 7)) * 8));
      f32x4 s4 = {};
      s4 = MFMA_BF16(kf0, qf0, s4);
      s4 = MFMA_BF16(kf1, qf1, s4);
      sc[kc] = s4;
    }
    float p[8][4];
#pragma unroll
    for (int kc = 0; kc < 8; kc++)
#pragma unroll
      for (int r = 0; r < 4; r++) p[kc][r] = sc[kc][r];
    if (ids) {
#pragma unroll
      for (int kc = 0; kc < 8; kc++) {
        int4 kid4 = *(const int4*)(Kid[cur] + kc * 16 + g * 4);
        if (kid4.x != qid) p[kc][0] = -1e30f;
        if (kid4.y != qid) p[kc][1] = -1e30f;
        if (kid4.z != qid) p[kc][2] = -1e30f;
        if (kid4.w != qid) p[kc][3] = -1e30f;
      }
    }
    float mx = fmaxf(fmaxf(p[0][0], p[0][1]), fmaxf(p[0][2], p[0][3]));
#pragma unroll
    for (int kc = 1; kc < 8; kc++)
      mx = fmaxf(mx, fmaxf(fmaxf(p[kc][0], p[kc][1]), fmaxf(p[kc][2], p[kc][3])));
    mx = fmaxf(mx, __shfl_xor(mx, 16, 64));
    mx = fmaxf(mx, __shfl_xor(mx, 32, 64));
    if (__any(mx > m_ + 8.f)) {   // defer-max
      float nm = fmaxf(m_, mx);
      float c = exp2f(m_ - nm);
      m_ = nm;
      l_ *= c;
#pragma unroll
      for (int r = 0; r < 4; r++) {
        float cr = __shfl(c, g * 4 + r, 16);
        oacc[0][r] *= cr; oacc[1][r] *= cr; oacc[2][r] *= cr; oacc[3][r] *= cr;
      }
    }
    float sum = 0.f;
#pragma unroll
    for (int kc = 0; kc < 8; kc++)
#pragma unroll
      for (int r = 0; r < 4; r++) {
        p[kc][r] = exp2f(p[kc][r] - m_);
        sum += p[kc][r];
      }
    sum += __shfl_xor(sum, 16, 64);
    sum += __shfl_xor(sum, 32, 64);
    l_ += sum;
    // PV: pack P via v_cvt_pk_bf16_f32 (2 f32 -> 1 dword); single b128 V frags
#pragma unroll
    for (int kk = 0; kk < 2; kk++) {
      u32x4 ua, ub;
      ua[0] = cvtpk(p[kk * 4 + 0][0], p[kk * 4 + 0][1]);
      ua[1] = cvtpk(p[kk * 4 + 0][2], p[kk * 4 + 0][3]);
      ua[2] = cvtpk(p[kk * 4 + 1][0], p[kk * 4 + 1][1]);
      ua[3] = cvtpk(p[kk * 4 + 1][2], p[kk * 4 + 1][3]);
      ub[0] = cvtpk(p[kk * 4 + 2][0], p[kk * 4 + 2][1]);
      ub[1] = cvtpk(p[kk * 4 + 2][2], p[kk * 4 + 2][3]);
      ub[2] = cvtpk(p[kk * 4 + 3][0], p[kk * 4 + 3][1]);
      ub[3] = cvtpk(p[kk * 4 + 3][2], p[kk * 4 + 3][3]);
      s16x8 pa = __builtin_bit_cast(s16x8, ua);
      s16x8 pb = __builtin_bit_cast(s16x8, ub);
#pragma unroll
      for (int dt = 0; dt < 4; dt++) {
        int dl = dt * 16 + qi;
        const short* vr = Vl[cur] + dl * 128;
        s16x8 vf0 = *(const s16x8*)(vr + (kk * 8 + (g ^ (dl & 7))) * 8);
        s16x8 vf1 = *(const s16x8*)(vr + (kk * 8 + ((4 + g) ^ (dl & 7))) * 8);
        oacc[dt] = MFMA_BF16(pa, vf0, oacc[dt]);
        oacc[dt] = MFMA_BF16(pb, vf1, oacc[dt]);
      }
    }
    __syncthreads();  // drains prefetch; all reads of [cur] done
    cur ^= 1;
  }
#undef STAGE_ATTN
  const size_t obase = (size_t)(bb * SEQ) * DM + hh * 64;
#pragma unroll
  for (int r = 0; r < 4; r++) {
    float lr = __shfl(l_, g * 4 + r, 16);
    float inv = 1.0f / lr;
    int q = q0 + w * 16 + g * 4 + r;
#pragma unroll
    for (int dt = 0; dt < 4; dt++)
      Ob[obase + (size_t)q * DM + dt * 16 + qi] = f2b(oacc[dt][r] * inv);
  }
}

// ---------------- host ----------------
extern "C" void kernel_launch(void* const* d_in, const int* in_sizes, int n_in,
                              void* d_out, int out_size, void* d_ws, size_t ws_size,
                              hipStream_t stream) {
  const float* x_in  = (const float*)d_in[0];
  const int* col_ids = (const int*)d_in[1];
  const int* row_ids = (const int*)d_in[2];
  const int* nbr_ids = (const int*)d_in[3];
  const float* g_attn = (const float*)d_in[11];
  const float* g_ffn  = (const float*)d_in[12];
  const float* g_out  = (const float*)d_in[13];

  char* ws = (char*)d_ws;
  float* x    = (float*)(ws);
  short* h    = (short*)(ws + (size_t)(8u  << 20));
  short* qkv  = (short*)(ws + (size_t)(12u << 20));
  short* vt   = (short*)(ws + (size_t)(24u << 20));
  short* ob   = (short*)(ws + (size_t)(28u << 20));
  float* sbuf = (float*)(ws + (size_t)(33u << 20));   // 21 slots x 4096 fp32
  short* fa   = (short*)(ws + (size_t)(44u << 20));
  short* wqkv = (short*)(ws + (size_t)(60u  << 20));  // [16][1536][512]
  short* wob  = (short*)(ws + (size_t)(84u  << 20));  // [16][512][512]
  short* w13  = (short*)(ws + (size_t)(92u  << 20));  // [4][4096][512] interleaved
  short* w2b  = (short*)(ws + (size_t)(108u << 20));  // [4][512][2048]

  cvt_all<<<dim3(4096, 8), 256, 0, stream>>>((const f32x4*)d_in[4], (const f32x4*)d_in[5],
                                             (const f32x4*)d_in[6], (const f32x4*)d_in[7],
                                             (const f32x4*)d_in[8], (const f32x4*)d_in[9],
                                             (const f32x4*)d_in[10], g_attn, g_ffn,
                                             (s16x4*)wqkv, (s16x4*)wob, (s16x4*)w13, (s16x4*)w2b,
                                             x_in, x, h, sbuf);

  const int* idsarr[4] = {col_ids, row_ids, nbr_ids, nullptr};

  for (int l = 0; l < 4; l++) {
    for (int r = 0; r < 4; r++) {
      int slot = l * 5 + r;
      size_t woff = (size_t)(l * 4 + r) * 1536 * DM;
      gemm_bt<4, 2, 2><<<dim3(32, 24), 256, 0, stream>>>(h, wqkv + woff, qkv, nullptr, vt,
                                                         sbuf + (size_t)slot * 4096, nullptr,
                                                         nullptr, 1536, DM);
      attn_kernel<<<dim3(32, 16), 256, 0, stream>>>(qkv, vt, idsarr[r], ob);
      gemm_bt<2, 2, 1><<<dim3(64, 8), 256, 0, stream>>>(ob, wob + (size_t)(l * 4 + r) * DM * DM,
                                                        nullptr, x, nullptr, nullptr,
                                                        sbuf + (size_t)(slot + 1) * 4096, h, DM, DM);
    }
    int fslot = l * 5 + 4;
    gemm_bt<4, 2, 3><<<dim3(32, 64), 256, 0, stream>>>(h, w13 + (size_t)l * 4096 * DM, fa, nullptr,
                                                       nullptr, sbuf + (size_t)fslot * 4096,
                                                       nullptr, nullptr, 4096, DM);
    gemm_bt<2, 2, 1><<<dim3(64, 8), 256, 0, stream>>>(fa, w2b + (size_t)l * DM * 2048, nullptr, x,
                                                      nullptr, nullptr,
                                                      sbuf + (size_t)(fslot + 1) * 4096, h, DM, 2048);
  }
  rmsnorm_out<<<1024, 256, 0, stream>>>(x, g_out, (float*)d_out);
}